// Round 1
// baseline (1934.754 us; speedup 1.0000x reference)
//
#include <hip/hip_runtime.h>
#include <hip/hip_bf16.h>

// GCN: 3x GCNConv(H=64) + global mean pool + linear head.
// Layer 1 is rank-1 (x is [N,1]) -> scalar edge aggregation.
// Layers 2,3: aggregate-first (A_norm @ h) with f32 atomics, then small GEMM.
// Final GEMM fused with relu + fc dot + per-graph pooling atomics.

#define WS_ALIGN(x) (((x) + 255) & ~size_t(255))

__global__ __launch_bounds__(256) void k_init(int n, int g, int* degi, float* s,
                                              float* gsum, float* gcnt) {
    int i = blockIdx.x * blockDim.x + threadIdx.x;
    if (i < n) { degi[i] = 1; s[i] = 0.f; }   // deg starts at 1 (self-loop)
    if (i < g) { gsum[i] = 0.f; gcnt[i] = 0.f; }
}

__global__ __launch_bounds__(256) void k_deg(int e, const int* __restrict__ dst,
                                             int* __restrict__ degi) {
    int i = blockIdx.x * blockDim.x + threadIdx.x;
    if (i < e) atomicAdd(&degi[dst[i]], 1);
}

__global__ __launch_bounds__(256) void k_dinv(int n, const int* __restrict__ degi,
                                              float* __restrict__ dinv) {
    int i = blockIdx.x * blockDim.x + threadIdx.x;
    if (i < n) dinv[i] = 1.0f / sqrtf((float)degi[i]);   // deg >= 1 always
}

// Layer-1 scalar edge aggregation: s[dst] += x[src] * dinv[src] * dinv[dst]
__global__ __launch_bounds__(256) void k_s(int e, const int* __restrict__ src,
                                           const int* __restrict__ dst,
                                           const float* __restrict__ x,
                                           const float* __restrict__ dinv,
                                           float* __restrict__ s) {
    int i = blockIdx.x * blockDim.x + threadIdx.x;
    if (i >= e) return;
    int u = src[i], v = dst[i];
    atomicAdd(&s[v], x[u] * dinv[u] * dinv[v]);
}

// h1[i][j] = relu((s[i] + x[i]*dinv^2) * w1[j] + b1[j]); also init agg2 = h1*dinv^2
__global__ __launch_bounds__(256) void k_h1(int n, const float* __restrict__ x,
                                            const float* __restrict__ s,
                                            const float* __restrict__ dinv,
                                            const float* __restrict__ w1,
                                            const float* __restrict__ b1,
                                            float* __restrict__ h1,
                                            float* __restrict__ agg) {
    int t = blockIdx.x * blockDim.x + threadIdx.x;
    if (t >= n * 64) return;
    int i = t >> 6, j = t & 63;
    float di = dinv[i];
    float st = s[i] + x[i] * di * di;
    float v = fmaxf(st * w1[j] + b1[j], 0.f);
    h1[t] = v;
    agg[t] = v * di * di;
}

// Edge aggregation for H=64: one wave per edge, lane = feature.
// agg[dst][j] += h[src][j] * dinv[src]*dinv[dst]
__global__ __launch_bounds__(256) void k_edge(int e, const int* __restrict__ src,
                                              const int* __restrict__ dst,
                                              const float* __restrict__ dinv,
                                              const float* __restrict__ h,
                                              float* __restrict__ agg) {
    int idx = blockIdx.x * blockDim.x + threadIdx.x;
    if (idx >= e * 64) return;
    int ei = idx >> 6, j = idx & 63;
    int u = src[ei], v = dst[ei];
    float nrm = dinv[u] * dinv[v];
    atomicAdd(&agg[v * 64 + j], h[u * 64 + j] * nrm);
}

// h_out = relu(agg @ w + b); also re-init agg (in place) to h_out*dinv^2 for next layer.
// Safe in-place: each block stages its 4 rows in LDS before any write.
__global__ __launch_bounds__(256) void k_gemm_mid(int n, const float* __restrict__ agg,
                                                  const float* __restrict__ w,
                                                  const float* __restrict__ b,
                                                  const float* __restrict__ dinv,
                                                  float* __restrict__ hout,
                                                  float* __restrict__ aggnext) {
    __shared__ float ws[64 * 64];
    __shared__ float rows[4 * 64];
    int tid = threadIdx.x;
    for (int k = tid; k < 64 * 64; k += 256) ws[k] = w[k];
    int r = tid >> 6, j = tid & 63;
    int i = blockIdx.x * 4 + r;
    if (i < n) rows[tid] = agg[i * 64 + j];
    __syncthreads();
    if (i >= n) return;
    float acc = b[j];
#pragma unroll
    for (int k = 0; k < 64; k++) acc += rows[r * 64 + k] * ws[k * 64 + j];
    float v = fmaxf(acc, 0.f);
    float di = dinv[i];
    hout[i * 64 + j] = v;
    aggnext[i * 64 + j] = v * di * di;
}

// Final layer: v = relu(agg @ w3 + b3); dot = v . fc_w; pool into gsum[batch[i]].
__global__ __launch_bounds__(256) void k_gemm_final(int n, const float* __restrict__ agg,
                                                    const float* __restrict__ w,
                                                    const float* __restrict__ b,
                                                    const float* __restrict__ fcw,
                                                    const int* __restrict__ batch,
                                                    float* __restrict__ gsum,
                                                    float* __restrict__ gcnt) {
    __shared__ float ws[64 * 64];
    __shared__ float rows[4 * 64];
    int tid = threadIdx.x;
    for (int k = tid; k < 64 * 64; k += 256) ws[k] = w[k];
    int r = tid >> 6, j = tid & 63;
    int i = blockIdx.x * 4 + r;
    if (i < n) rows[tid] = agg[i * 64 + j];
    __syncthreads();
    if (i >= n) return;
    float acc = b[j];
#pragma unroll
    for (int k = 0; k < 64; k++) acc += rows[r * 64 + k] * ws[k * 64 + j];
    float v = fmaxf(acc, 0.f) * fcw[j];
    // wave-wide (64-lane) sum; each wave is exactly one row
#pragma unroll
    for (int o = 32; o > 0; o >>= 1) v += __shfl_down(v, o, 64);
    if (j == 0) {
        int g = batch[i];
        atomicAdd(&gsum[g], v);
        atomicAdd(&gcnt[g], 1.0f);
    }
}

__global__ __launch_bounds__(256) void k_out(int g, const float* __restrict__ gsum,
                                             const float* __restrict__ gcnt,
                                             const float* __restrict__ fcb,
                                             float* __restrict__ out) {
    int i = blockIdx.x * blockDim.x + threadIdx.x;
    if (i < g) out[i] = gsum[i] / fmaxf(gcnt[i], 1.f) + fcb[0];
}

extern "C" void kernel_launch(void* const* d_in, const int* in_sizes, int n_in,
                              void* d_out, int out_size, void* d_ws, size_t ws_size,
                              hipStream_t stream) {
    const float* x    = (const float*)d_in[0];
    const int*   ei   = (const int*)d_in[1];
    const int*   batch= (const int*)d_in[2];
    const float* w1   = (const float*)d_in[3];
    const float* b1   = (const float*)d_in[4];
    const float* w2   = (const float*)d_in[5];
    const float* b2   = (const float*)d_in[6];
    const float* w3   = (const float*)d_in[7];
    const float* b3   = (const float*)d_in[8];
    const float* fcw  = (const float*)d_in[9];
    const float* fcb  = (const float*)d_in[10];
    float* out = (float*)d_out;

    const int N = in_sizes[0];          // x is [N,1]
    const int E = in_sizes[1] / 2;      // edge_index [2,E]
    const int G = out_size;             // [G,1] output
    const int H = 64;                   // hidden dim (hardcoded: kernels use &63,>>6)

    const int* src = ei;
    const int* dst = ei + E;

    // workspace carve-up
    char* p = (char*)d_ws;
    int*   degi = (int*)p;              p += WS_ALIGN(sizeof(int) * N);
    float* dinv = (float*)p;            p += WS_ALIGN(sizeof(float) * N);
    float* s    = (float*)p;            p += WS_ALIGN(sizeof(float) * N);
    float* bufA = (float*)p;            p += WS_ALIGN(sizeof(float) * (size_t)N * H);
    float* bufB = (float*)p;            p += WS_ALIGN(sizeof(float) * (size_t)N * H);
    float* gsum = (float*)p;            p += WS_ALIGN(sizeof(float) * G);
    float* gcnt = (float*)p;            p += WS_ALIGN(sizeof(float) * G);

    const int B = 256;
    int gridN  = (N + B - 1) / B;
    int gridE  = (E + B - 1) / B;
    int gridNH = (N * H + B - 1) / B;
    int gridEH = (int)(((long long)E * H + B - 1) / B);
    int gridR  = (N + 3) / 4;           // 4 rows per block in GEMM kernels
    int gridG  = (G + B - 1) / B;
    int gridInit = ((N > G ? N : G) + B - 1) / B;

    k_init<<<gridInit, B, 0, stream>>>(N, G, degi, s, gsum, gcnt);
    k_deg<<<gridE, B, 0, stream>>>(E, dst, degi);
    k_dinv<<<gridN, B, 0, stream>>>(N, degi, dinv);
    k_s<<<gridE, B, 0, stream>>>(E, src, dst, x, dinv, s);
    k_h1<<<gridNH, B, 0, stream>>>(N, x, s, dinv, w1, b1, bufA, bufB);
    // layer 2: aggregate h1 over edges into bufB (self-loop already in bufB)
    k_edge<<<gridEH, B, 0, stream>>>(E, src, dst, dinv, bufA, bufB);
    // h2 = relu(agg2 @ w2 + b2) -> bufA; bufB re-init to h2*dinv^2 (agg3 self-loop)
    k_gemm_mid<<<gridR, B, 0, stream>>>(N, bufB, w2, b2, dinv, bufA, bufB);
    // layer 3: aggregate h2 over edges into bufB
    k_edge<<<gridEH, B, 0, stream>>>(E, src, dst, dinv, bufA, bufB);
    // h3 = relu(agg3 @ w3 + b3), fused fc dot + mean-pool accumulate
    k_gemm_final<<<gridR, B, 0, stream>>>(N, bufB, w3, b3, fcw, batch, gsum, gcnt);
    k_out<<<gridG, B, 0, stream>>>(G, gsum, gcnt, fcb, out);
}

// Round 2
// 853.620 us; speedup vs baseline: 2.2665x; 2.2665x over previous
//
#include <hip/hip_runtime.h>
#include <hip/hip_bf16.h>

// GCN: 3x GCNConv(H=64) + global mean pool + linear head.
// Round 1 -> 2: replace f32 atomic scatter (atomic-pipe-bound, 800MB write-through
// per layer) with CSR build + per-node gather (no atomics in the hot loops).

#define WS_ALIGN(x) (((x) + 255) & ~size_t(255))

// ---- init: degi=1 (self-loop), cursor=0, pool accumulators=0 ----
__global__ __launch_bounds__(256) void k_init(int n, int g, int* degi, int* cursor,
                                              float* gsum, float* gcnt) {
    int i = blockIdx.x * blockDim.x + threadIdx.x;
    if (i < n) { degi[i] = 1; cursor[i] = 0; }
    if (i < g) { gsum[i] = 0.f; gcnt[i] = 0.f; }
}

__global__ __launch_bounds__(256) void k_deg(int e, const int* __restrict__ dst,
                                             int* __restrict__ degi) {
    int i = blockIdx.x * blockDim.x + threadIdx.x;
    if (i < e) atomicAdd(&degi[dst[i]], 1);
}

// dinv = 1/sqrt(deg); xs = x*dinv (pre-scaled source values for layer-1 gather)
__global__ __launch_bounds__(256) void k_dinv(int n, const int* __restrict__ degi,
                                              const float* __restrict__ x,
                                              float* __restrict__ dinv,
                                              float* __restrict__ xs) {
    int i = blockIdx.x * blockDim.x + threadIdx.x;
    if (i >= n) return;
    float di = 1.0f / sqrtf((float)degi[i]);   // deg >= 1 always
    dinv[i] = di;
    xs[i] = x[i] * di;
}

// ---- CSR build: exclusive scan of in-degree (degi-1) into start[] ----
// scan1: each block scans a 1024-node chunk; psum[b] = chunk total
__global__ __launch_bounds__(256) void k_scan1(int n, const int* __restrict__ degi,
                                               int* __restrict__ start,
                                               int* __restrict__ psum) {
    __shared__ int sd[256];
    int tid = threadIdx.x;
    int i0 = blockIdx.x * 1024 + tid * 4;
    int a = (i0 + 0 < n) ? degi[i0 + 0] - 1 : 0;
    int b = (i0 + 1 < n) ? degi[i0 + 1] - 1 : 0;
    int c = (i0 + 2 < n) ? degi[i0 + 2] - 1 : 0;
    int d = (i0 + 3 < n) ? degi[i0 + 3] - 1 : 0;
    int tsum = a + b + c + d;
    sd[tid] = tsum;
    __syncthreads();
    for (int off = 1; off < 256; off <<= 1) {
        int v = (tid >= off) ? sd[tid - off] : 0;
        __syncthreads();
        sd[tid] += v;
        __syncthreads();
    }
    int excl = sd[tid] - tsum;
    if (i0 + 0 < n) start[i0 + 0] = excl;
    if (i0 + 1 < n) start[i0 + 1] = excl + a;
    if (i0 + 2 < n) start[i0 + 2] = excl + a + b;
    if (i0 + 3 < n) start[i0 + 3] = excl + a + b + c;
    if (tid == 255) psum[blockIdx.x] = sd[255];
}

// scan2: single block, exclusive-scan psum in place (supports up to 1024 chunks)
__global__ __launch_bounds__(256) void k_scan2(int nchunks, int* __restrict__ psum) {
    __shared__ int sd[256];
    int tid = threadIdx.x;
    int i0 = tid * 4;
    int a = (i0 + 0 < nchunks) ? psum[i0 + 0] : 0;
    int b = (i0 + 1 < nchunks) ? psum[i0 + 1] : 0;
    int c = (i0 + 2 < nchunks) ? psum[i0 + 2] : 0;
    int d = (i0 + 3 < nchunks) ? psum[i0 + 3] : 0;
    int tsum = a + b + c + d;
    sd[tid] = tsum;
    __syncthreads();
    for (int off = 1; off < 256; off <<= 1) {
        int v = (tid >= off) ? sd[tid - off] : 0;
        __syncthreads();
        sd[tid] += v;
        __syncthreads();
    }
    int excl = sd[tid] - tsum;
    if (i0 + 0 < nchunks) psum[i0 + 0] = excl;
    if (i0 + 1 < nchunks) psum[i0 + 1] = excl + a;
    if (i0 + 2 < nchunks) psum[i0 + 2] = excl + a + b;
    if (i0 + 3 < nchunks) psum[i0 + 3] = excl + a + b + c;
}

// scan3: add chunk offsets; start[n] = e
__global__ __launch_bounds__(256) void k_scan3(int n, int e, int* __restrict__ start,
                                               const int* __restrict__ psum) {
    int i = blockIdx.x * blockDim.x + threadIdx.x;
    if (i < n) start[i] += psum[i >> 10];
    if (i == n) start[n] = e;
}

// scatter edges into CSR by dst (order within a row is arbitrary -> rounding only)
__global__ __launch_bounds__(256) void k_scatter(int e, const int* __restrict__ src,
                                                 const int* __restrict__ dst,
                                                 const int* __restrict__ start,
                                                 int* __restrict__ cursor,
                                                 int* __restrict__ csr) {
    int i = blockIdx.x * blockDim.x + threadIdx.x;
    if (i >= e) return;
    int v = dst[i];
    int pos = start[v] + atomicAdd(&cursor[v], 1);
    csr[pos] = src[i];
}

// ---- layer 1 (rank-1): s[v] = (sum_in xs[u] + xs[v]) * dinv[v]  (one wave/node)
__global__ __launch_bounds__(256) void k_gather_s(int n, const int* __restrict__ start,
                                                  const int* __restrict__ csr,
                                                  const float* __restrict__ xs,
                                                  const float* __restrict__ dinv,
                                                  float* __restrict__ s) {
    int v = blockIdx.x * 4 + (threadIdx.x >> 6);
    int lane = threadIdx.x & 63;
    if (v >= n) return;
    int s0 = start[v], s1 = start[v + 1];
    float acc = 0.f;
    for (int k = s0 + lane; k < s1; k += 64) acc += xs[csr[k]];
#pragma unroll
    for (int m = 32; m > 0; m >>= 1) acc += __shfl_xor(acc, m, 64);
    if (lane == 0) s[v] = (acc + xs[v]) * dinv[v];
}

// h1 from scalar aggregate; write hs1 = relu(s*w1+b1)*dinv directly
__global__ __launch_bounds__(256) void k_h1(int n, const float* __restrict__ s,
                                            const float* __restrict__ dinv,
                                            const float* __restrict__ w1,
                                            const float* __restrict__ b1,
                                            float* __restrict__ hs) {
    int t = blockIdx.x * blockDim.x + threadIdx.x;
    if (t >= n * 64) return;
    int i = t >> 6, j = t & 63;
    float v = fmaxf(s[i] * w1[j] + b1[j], 0.f);
    hs[t] = v * dinv[i];
}

// ---- H=64 gather: agg[v][j] = dinv[v] * (sum_in hs[u][j] + hs[v][j]) ----
// one wave per node, lane=feature; edge ids staged per-lane + shfl broadcast,
// 4 independent accumulator chains for memory-level parallelism.
__global__ __launch_bounds__(256) void k_gather64(int n, const int* __restrict__ start,
                                                  const int* __restrict__ csr,
                                                  const float* __restrict__ hs,
                                                  const float* __restrict__ dinv,
                                                  float* __restrict__ agg) {
    int v = blockIdx.x * 4 + (threadIdx.x >> 6);
    int lane = threadIdx.x & 63;
    if (v >= n) return;
    int s0 = start[v], s1 = start[v + 1];
    float a0 = hs[v * 64 + lane], a1 = 0.f, a2 = 0.f, a3 = 0.f;
    for (int base = s0; base < s1; base += 64) {
        int k = base + lane;
        int u = (k < s1) ? csr[k] : 0;
        int m = s1 - base; if (m > 64) m = 64;
        int t = 0;
        for (; t + 4 <= m; t += 4) {
            int u0 = __shfl(u, t, 64);
            int u1 = __shfl(u, t + 1, 64);
            int u2 = __shfl(u, t + 2, 64);
            int u3 = __shfl(u, t + 3, 64);
            a0 += hs[u0 * 64 + lane];
            a1 += hs[u1 * 64 + lane];
            a2 += hs[u2 * 64 + lane];
            a3 += hs[u3 * 64 + lane];
        }
        for (; t < m; ++t) {
            int u0 = __shfl(u, t, 64);
            a0 += hs[u0 * 64 + lane];
        }
    }
    agg[v * 64 + lane] = ((a0 + a1) + (a2 + a3)) * dinv[v];
}

// h_out = relu(agg @ w + b); write hs_out = h_out * dinv for the next gather
__global__ __launch_bounds__(256) void k_gemm_mid(int n, const float* __restrict__ agg,
                                                  const float* __restrict__ w,
                                                  const float* __restrict__ b,
                                                  const float* __restrict__ dinv,
                                                  float* __restrict__ hsout) {
    __shared__ float ws[64 * 64];
    __shared__ float rows[4 * 64];
    int tid = threadIdx.x;
    for (int k = tid; k < 64 * 64; k += 256) ws[k] = w[k];
    int r = tid >> 6, j = tid & 63;
    int i = blockIdx.x * 4 + r;
    if (i < n) rows[tid] = agg[i * 64 + j];
    __syncthreads();
    if (i >= n) return;
    float acc = b[j];
#pragma unroll
    for (int k = 0; k < 64; k++) acc += rows[r * 64 + k] * ws[k * 64 + j];
    hsout[i * 64 + j] = fmaxf(acc, 0.f) * dinv[i];
}

// final: v = relu(agg @ w3 + b3); dot with fc_w; pool into gsum[batch[i]]
__global__ __launch_bounds__(256) void k_gemm_final(int n, const float* __restrict__ agg,
                                                    const float* __restrict__ w,
                                                    const float* __restrict__ b,
                                                    const float* __restrict__ fcw,
                                                    const int* __restrict__ batch,
                                                    float* __restrict__ gsum,
                                                    float* __restrict__ gcnt) {
    __shared__ float ws[64 * 64];
    __shared__ float rows[4 * 64];
    int tid = threadIdx.x;
    for (int k = tid; k < 64 * 64; k += 256) ws[k] = w[k];
    int r = tid >> 6, j = tid & 63;
    int i = blockIdx.x * 4 + r;
    if (i < n) rows[tid] = agg[i * 64 + j];
    __syncthreads();
    if (i >= n) return;
    float acc = b[j];
#pragma unroll
    for (int k = 0; k < 64; k++) acc += rows[r * 64 + k] * ws[k * 64 + j];
    float v = fmaxf(acc, 0.f) * fcw[j];
#pragma unroll
    for (int o = 32; o > 0; o >>= 1) v += __shfl_down(v, o, 64);
    if (j == 0) {
        int g = batch[i];
        atomicAdd(&gsum[g], v);
        atomicAdd(&gcnt[g], 1.0f);
    }
}

__global__ __launch_bounds__(256) void k_out(int g, const float* __restrict__ gsum,
                                             const float* __restrict__ gcnt,
                                             const float* __restrict__ fcb,
                                             float* __restrict__ out) {
    int i = blockIdx.x * blockDim.x + threadIdx.x;
    if (i < g) out[i] = gsum[i] / fmaxf(gcnt[i], 1.f) + fcb[0];
}

extern "C" void kernel_launch(void* const* d_in, const int* in_sizes, int n_in,
                              void* d_out, int out_size, void* d_ws, size_t ws_size,
                              hipStream_t stream) {
    const float* x    = (const float*)d_in[0];
    const int*   ei   = (const int*)d_in[1];
    const int*   batch= (const int*)d_in[2];
    const float* w1   = (const float*)d_in[3];
    const float* b1   = (const float*)d_in[4];
    const float* w2   = (const float*)d_in[5];
    const float* b2   = (const float*)d_in[6];
    const float* w3   = (const float*)d_in[7];
    const float* b3   = (const float*)d_in[8];
    const float* fcw  = (const float*)d_in[9];
    const float* fcb  = (const float*)d_in[10];
    float* out = (float*)d_out;

    const int N = in_sizes[0];
    const int E = in_sizes[1] / 2;
    const int G = out_size;
    const int H = 64;

    const int* src = ei;
    const int* dst = ei + E;

    // workspace carve-up (~67 MB)
    char* p = (char*)d_ws;
    int*   degi   = (int*)p;   p += WS_ALIGN(sizeof(int) * N);
    int*   cursor = (int*)p;   p += WS_ALIGN(sizeof(int) * N);
    int*   start  = (int*)p;   p += WS_ALIGN(sizeof(int) * (N + 1));
    int*   psum   = (int*)p;   p += WS_ALIGN(sizeof(int) * 1024);
    int*   csr    = (int*)p;   p += WS_ALIGN(sizeof(int) * (size_t)E);
    float* dinv   = (float*)p; p += WS_ALIGN(sizeof(float) * N);
    float* xs     = (float*)p; p += WS_ALIGN(sizeof(float) * N);
    float* s      = (float*)p; p += WS_ALIGN(sizeof(float) * N);
    float* bufA   = (float*)p; p += WS_ALIGN(sizeof(float) * (size_t)N * H);
    float* bufB   = (float*)p; p += WS_ALIGN(sizeof(float) * (size_t)N * H);
    float* gsum   = (float*)p; p += WS_ALIGN(sizeof(float) * G);
    float* gcnt   = (float*)p; p += WS_ALIGN(sizeof(float) * G);

    const int B = 256;
    int gridN    = (N + B - 1) / B;
    int gridE    = (E + B - 1) / B;
    int gridNH   = (N * H + B - 1) / B;
    int gridWave = (N + 3) / 4;              // 4 waves (nodes) per block
    int gridG    = (G + B - 1) / B;
    int gridInit = ((N > G ? N : G) + B - 1) / B;
    int nchunks  = (N + 1023) / 1024;
    int gridS3   = (N + 1 + B - 1) / B;

    k_init<<<gridInit, B, 0, stream>>>(N, G, degi, cursor, gsum, gcnt);
    k_deg<<<gridE, B, 0, stream>>>(E, dst, degi);
    k_dinv<<<gridN, B, 0, stream>>>(N, degi, x, dinv, xs);
    // CSR build
    k_scan1<<<nchunks, B, 0, stream>>>(N, degi, start, psum);
    k_scan2<<<1, B, 0, stream>>>(nchunks, psum);
    k_scan3<<<gridS3, B, 0, stream>>>(N, E, start, psum);
    k_scatter<<<gridE, B, 0, stream>>>(E, src, dst, start, cursor, csr);
    // layer 1 (rank-1)
    k_gather_s<<<gridWave, B, 0, stream>>>(N, start, csr, xs, dinv, s);
    k_h1<<<gridNH, B, 0, stream>>>(N, s, dinv, w1, b1, bufA);
    // layer 2
    k_gather64<<<gridWave, B, 0, stream>>>(N, start, csr, bufA, dinv, bufB);
    k_gemm_mid<<<gridWave, B, 0, stream>>>(N, bufB, w2, b2, dinv, bufA);
    // layer 3
    k_gather64<<<gridWave, B, 0, stream>>>(N, start, csr, bufA, dinv, bufB);
    k_gemm_final<<<gridWave, B, 0, stream>>>(N, bufB, w3, b3, fcw, batch, gsum, gcnt);
    k_out<<<gridG, B, 0, stream>>>(G, gsum, gcnt, fcb, out);
}

// Round 3
// 836.249 us; speedup vs baseline: 2.3136x; 1.0208x over previous
//
#include <hip/hip_runtime.h>
#include <hip/hip_bf16.h>

// GCN: 3x GCNConv(H=64) + global mean pool + linear head.
// Round 2 -> 3: fuse GEMM into the gather kernels (agg row stays in the wave),
// swizzled float4 transposed weights in LDS, dots[] + LDS-binned pooling
// (removes contended global atomics and the agg write/read round trips).

#define WS_ALIGN(x) (((x) + 255) & ~size_t(255))

__global__ __launch_bounds__(256) void k_init(int n, int g, int* degi, int* cursor,
                                              float* gsum, float* gcnt) {
    int i = blockIdx.x * blockDim.x + threadIdx.x;
    if (i < n) { degi[i] = 1; cursor[i] = 0; }
    if (i < g) { gsum[i] = 0.f; gcnt[i] = 0.f; }
}

__global__ __launch_bounds__(256) void k_deg(int e, const int* __restrict__ dst,
                                             int* __restrict__ degi) {
    int i = blockIdx.x * blockDim.x + threadIdx.x;
    if (i < e) atomicAdd(&degi[dst[i]], 1);
}

__global__ __launch_bounds__(256) void k_dinv(int n, const int* __restrict__ degi,
                                              const float* __restrict__ x,
                                              float* __restrict__ dinv,
                                              float* __restrict__ xs) {
    int i = blockIdx.x * blockDim.x + threadIdx.x;
    if (i >= n) return;
    float di = 1.0f / sqrtf((float)degi[i]);   // deg >= 1 always
    dinv[i] = di;
    xs[i] = x[i] * di;
}

// ---- CSR build (in-degree exclusive scan + cursor scatter) ----
__global__ __launch_bounds__(256) void k_scan1(int n, const int* __restrict__ degi,
                                               int* __restrict__ start,
                                               int* __restrict__ psum) {
    __shared__ int sd[256];
    int tid = threadIdx.x;
    int i0 = blockIdx.x * 1024 + tid * 4;
    int a = (i0 + 0 < n) ? degi[i0 + 0] - 1 : 0;
    int b = (i0 + 1 < n) ? degi[i0 + 1] - 1 : 0;
    int c = (i0 + 2 < n) ? degi[i0 + 2] - 1 : 0;
    int d = (i0 + 3 < n) ? degi[i0 + 3] - 1 : 0;
    int tsum = a + b + c + d;
    sd[tid] = tsum;
    __syncthreads();
    for (int off = 1; off < 256; off <<= 1) {
        int v = (tid >= off) ? sd[tid - off] : 0;
        __syncthreads();
        sd[tid] += v;
        __syncthreads();
    }
    int excl = sd[tid] - tsum;
    if (i0 + 0 < n) start[i0 + 0] = excl;
    if (i0 + 1 < n) start[i0 + 1] = excl + a;
    if (i0 + 2 < n) start[i0 + 2] = excl + a + b;
    if (i0 + 3 < n) start[i0 + 3] = excl + a + b + c;
    if (tid == 255) psum[blockIdx.x] = sd[255];
}

__global__ __launch_bounds__(256) void k_scan2(int nchunks, int* __restrict__ psum) {
    __shared__ int sd[256];
    int tid = threadIdx.x;
    int i0 = tid * 4;
    int a = (i0 + 0 < nchunks) ? psum[i0 + 0] : 0;
    int b = (i0 + 1 < nchunks) ? psum[i0 + 1] : 0;
    int c = (i0 + 2 < nchunks) ? psum[i0 + 2] : 0;
    int d = (i0 + 3 < nchunks) ? psum[i0 + 3] : 0;
    int tsum = a + b + c + d;
    sd[tid] = tsum;
    __syncthreads();
    for (int off = 1; off < 256; off <<= 1) {
        int v = (tid >= off) ? sd[tid - off] : 0;
        __syncthreads();
        sd[tid] += v;
        __syncthreads();
    }
    int excl = sd[tid] - tsum;
    if (i0 + 0 < nchunks) psum[i0 + 0] = excl;
    if (i0 + 1 < nchunks) psum[i0 + 1] = excl + a;
    if (i0 + 2 < nchunks) psum[i0 + 2] = excl + a + b;
    if (i0 + 3 < nchunks) psum[i0 + 3] = excl + a + b + c;
}

__global__ __launch_bounds__(256) void k_scan3(int n, int e, int* __restrict__ start,
                                               const int* __restrict__ psum) {
    int i = blockIdx.x * blockDim.x + threadIdx.x;
    if (i < n) start[i] += psum[i >> 10];
    if (i == n) start[n] = e;
}

__global__ __launch_bounds__(256) void k_scatter(int e, const int* __restrict__ src,
                                                 const int* __restrict__ dst,
                                                 const int* __restrict__ start,
                                                 int* __restrict__ cursor,
                                                 int* __restrict__ csr) {
    int i = blockIdx.x * blockDim.x + threadIdx.x;
    if (i >= e) return;
    int v = dst[i];
    int pos = start[v] + atomicAdd(&cursor[v], 1);
    csr[pos] = src[i];
}

// ---- layer 1 (rank-1): s[v] = (sum_in xs[u] + xs[v]) * dinv[v] ----
__global__ __launch_bounds__(256) void k_gather_s(int n, const int* __restrict__ start,
                                                  const int* __restrict__ csr,
                                                  const float* __restrict__ xs,
                                                  const float* __restrict__ dinv,
                                                  float* __restrict__ s) {
    int v = blockIdx.x * 4 + (threadIdx.x >> 6);
    int lane = threadIdx.x & 63;
    if (v >= n) return;
    int s0 = start[v], s1 = start[v + 1];
    float acc = 0.f;
    for (int k = s0 + lane; k < s1; k += 64) acc += xs[csr[k]];
#pragma unroll
    for (int m = 32; m > 0; m >>= 1) acc += __shfl_xor(acc, m, 64);
    if (lane == 0) s[v] = (acc + xs[v]) * dinv[v];
}

// hs1 = relu(s*w1 + b1) * dinv
__global__ __launch_bounds__(256) void k_h1(int n, const float* __restrict__ s,
                                            const float* __restrict__ dinv,
                                            const float* __restrict__ w1,
                                            const float* __restrict__ b1,
                                            float* __restrict__ hs) {
    int t = blockIdx.x * blockDim.x + threadIdx.x;
    if (t >= n * 64) return;
    int i = t >> 6, j = t & 63;
    float v = fmaxf(s[i] * w1[j] + b1[j], 0.f);
    hs[t] = v * dinv[i];
}

// ---- fused layer: gather(+self) -> GEMM(w) -> relu -> *dinv ----
// one wave per node; agg row lives across the wave (lane = feature).
// wsT: transposed weights, float4 over k, XOR-swizzled to spread bank quads.
__global__ __launch_bounds__(256) void k_layer(int n, const int* __restrict__ start,
                                               const int* __restrict__ csr,
                                               const float* __restrict__ hs_in,
                                               const float* __restrict__ dinv,
                                               const float* __restrict__ w,
                                               const float* __restrict__ b,
                                               float* __restrict__ hs_out) {
    __shared__ float4 wsT[1024];          // [j][kg^] : w[4kg+c][j]
    __shared__ float rowl[4][64];
    int tid = threadIdx.x;
    for (int g = tid; g < 1024; g += 256) {
        int j = g >> 4, kg = g & 15;
        float4 wv;
        wv.x = w[(4 * kg + 0) * 64 + j];
        wv.y = w[(4 * kg + 1) * 64 + j];
        wv.z = w[(4 * kg + 2) * 64 + j];
        wv.w = w[(4 * kg + 3) * 64 + j];
        wsT[(j << 4) | (kg ^ (j & 7))] = wv;
    }
    int r = tid >> 6, lane = tid & 63;
    int v = blockIdx.x * 4 + r;
    if (v < n) {
        int s0 = start[v], s1 = start[v + 1];
        float a0 = hs_in[(size_t)v * 64 + lane];
        float a1 = 0.f, a2 = 0.f, a3 = 0.f, a4 = 0.f, a5 = 0.f, a6 = 0.f, a7 = 0.f;
        for (int base = s0; base < s1; base += 64) {
            int k = base + lane;
            int u = (k < s1) ? csr[k] : 0;
            int m = s1 - base; if (m > 64) m = 64;
            int t = 0;
            for (; t + 8 <= m; t += 8) {
                int u0 = __shfl(u, t, 64),     u1 = __shfl(u, t + 1, 64);
                int u2 = __shfl(u, t + 2, 64), u3 = __shfl(u, t + 3, 64);
                int u4 = __shfl(u, t + 4, 64), u5 = __shfl(u, t + 5, 64);
                int u6 = __shfl(u, t + 6, 64), u7 = __shfl(u, t + 7, 64);
                a0 += hs_in[(size_t)u0 * 64 + lane]; a1 += hs_in[(size_t)u1 * 64 + lane];
                a2 += hs_in[(size_t)u2 * 64 + lane]; a3 += hs_in[(size_t)u3 * 64 + lane];
                a4 += hs_in[(size_t)u4 * 64 + lane]; a5 += hs_in[(size_t)u5 * 64 + lane];
                a6 += hs_in[(size_t)u6 * 64 + lane]; a7 += hs_in[(size_t)u7 * 64 + lane];
            }
            for (; t < m; ++t) {
                int u0 = __shfl(u, t, 64);
                a0 += hs_in[(size_t)u0 * 64 + lane];
            }
        }
        rowl[r][lane] = (((a0 + a1) + (a2 + a3)) + ((a4 + a5) + (a6 + a7))) * dinv[v];
    }
    __syncthreads();
    if (v >= n) return;
    float acc = b[lane];
    const float4* row4 = (const float4*)&rowl[r][0];
    int jb = lane << 4, jx = lane & 7;
#pragma unroll
    for (int kg = 0; kg < 16; ++kg) {
        float4 a = row4[kg];
        float4 wv = wsT[jb | (kg ^ jx)];
        acc += a.x * wv.x + a.y * wv.y + a.z * wv.z + a.w * wv.w;
    }
    hs_out[(size_t)v * 64 + lane] = fmaxf(acc, 0.f) * dinv[v];
}

// final fused layer: gather -> GEMM(w3) -> relu -> dot(fcw) -> dots[v] (no atomics)
__global__ __launch_bounds__(256) void k_layer_final(int n, const int* __restrict__ start,
                                                     const int* __restrict__ csr,
                                                     const float* __restrict__ hs_in,
                                                     const float* __restrict__ dinv,
                                                     const float* __restrict__ w,
                                                     const float* __restrict__ b,
                                                     const float* __restrict__ fcw,
                                                     float* __restrict__ dots) {
    __shared__ float4 wsT[1024];
    __shared__ float rowl[4][64];
    int tid = threadIdx.x;
    for (int g = tid; g < 1024; g += 256) {
        int j = g >> 4, kg = g & 15;
        float4 wv;
        wv.x = w[(4 * kg + 0) * 64 + j];
        wv.y = w[(4 * kg + 1) * 64 + j];
        wv.z = w[(4 * kg + 2) * 64 + j];
        wv.w = w[(4 * kg + 3) * 64 + j];
        wsT[(j << 4) | (kg ^ (j & 7))] = wv;
    }
    int r = tid >> 6, lane = tid & 63;
    int v = blockIdx.x * 4 + r;
    if (v < n) {
        int s0 = start[v], s1 = start[v + 1];
        float a0 = hs_in[(size_t)v * 64 + lane];
        float a1 = 0.f, a2 = 0.f, a3 = 0.f, a4 = 0.f, a5 = 0.f, a6 = 0.f, a7 = 0.f;
        for (int base = s0; base < s1; base += 64) {
            int k = base + lane;
            int u = (k < s1) ? csr[k] : 0;
            int m = s1 - base; if (m > 64) m = 64;
            int t = 0;
            for (; t + 8 <= m; t += 8) {
                int u0 = __shfl(u, t, 64),     u1 = __shfl(u, t + 1, 64);
                int u2 = __shfl(u, t + 2, 64), u3 = __shfl(u, t + 3, 64);
                int u4 = __shfl(u, t + 4, 64), u5 = __shfl(u, t + 5, 64);
                int u6 = __shfl(u, t + 6, 64), u7 = __shfl(u, t + 7, 64);
                a0 += hs_in[(size_t)u0 * 64 + lane]; a1 += hs_in[(size_t)u1 * 64 + lane];
                a2 += hs_in[(size_t)u2 * 64 + lane]; a3 += hs_in[(size_t)u3 * 64 + lane];
                a4 += hs_in[(size_t)u4 * 64 + lane]; a5 += hs_in[(size_t)u5 * 64 + lane];
                a6 += hs_in[(size_t)u6 * 64 + lane]; a7 += hs_in[(size_t)u7 * 64 + lane];
            }
            for (; t < m; ++t) {
                int u0 = __shfl(u, t, 64);
                a0 += hs_in[(size_t)u0 * 64 + lane];
            }
        }
        rowl[r][lane] = (((a0 + a1) + (a2 + a3)) + ((a4 + a5) + (a6 + a7))) * dinv[v];
    }
    __syncthreads();
    if (v >= n) return;
    float acc = b[lane];
    const float4* row4 = (const float4*)&rowl[r][0];
    int jb = lane << 4, jx = lane & 7;
#pragma unroll
    for (int kg = 0; kg < 16; ++kg) {
        float4 a = row4[kg];
        float4 wv = wsT[jb | (kg ^ jx)];
        acc += a.x * wv.x + a.y * wv.y + a.z * wv.z + a.w * wv.w;
    }
    float val = fmaxf(acc, 0.f) * fcw[lane];
#pragma unroll
    for (int o = 32; o > 0; o >>= 1) val += __shfl_xor(val, o, 64);
    if (lane == 0) dots[v] = val;
}

// pooled accumulation: LDS-binned segmented reduce over sorted batch.
// block covers 1024 consecutive nodes (~11 graphs) -> few global atomics.
__global__ __launch_bounds__(256) void k_pool(int n, const float* __restrict__ dots,
                                              const int* __restrict__ batch,
                                              float* __restrict__ gsum,
                                              float* __restrict__ gcnt) {
    __shared__ float ls[64], lc[64];
    __shared__ int gmin_s;
    int tid = threadIdx.x;
    int i0 = blockIdx.x * 1024;
    if (tid == 0) gmin_s = batch[i0];
    if (tid < 64) { ls[tid] = 0.f; lc[tid] = 0.f; }
    __syncthreads();
    int gmin = gmin_s;
#pragma unroll
    for (int c = 0; c < 4; ++c) {
        int i = i0 + c * 256 + tid;
        if (i < n) {
            int g = batch[i];
            float d = dots[i];
            int rr = g - gmin;
            if (rr < 64) {
                atomicAdd(&ls[rr], d);
                atomicAdd(&lc[rr], 1.f);
            } else {
                atomicAdd(&gsum[g], d);
                atomicAdd(&gcnt[g], 1.f);
            }
        }
    }
    __syncthreads();
    if (tid < 64 && lc[tid] != 0.f) {
        atomicAdd(&gsum[gmin + tid], ls[tid]);
        atomicAdd(&gcnt[gmin + tid], lc[tid]);
    }
}

__global__ __launch_bounds__(256) void k_out(int g, const float* __restrict__ gsum,
                                             const float* __restrict__ gcnt,
                                             const float* __restrict__ fcb,
                                             float* __restrict__ out) {
    int i = blockIdx.x * blockDim.x + threadIdx.x;
    if (i < g) out[i] = gsum[i] / fmaxf(gcnt[i], 1.f) + fcb[0];
}

extern "C" void kernel_launch(void* const* d_in, const int* in_sizes, int n_in,
                              void* d_out, int out_size, void* d_ws, size_t ws_size,
                              hipStream_t stream) {
    const float* x    = (const float*)d_in[0];
    const int*   ei   = (const int*)d_in[1];
    const int*   batch= (const int*)d_in[2];
    const float* w1   = (const float*)d_in[3];
    const float* b1   = (const float*)d_in[4];
    const float* w2   = (const float*)d_in[5];
    const float* b2   = (const float*)d_in[6];
    const float* w3   = (const float*)d_in[7];
    const float* b3   = (const float*)d_in[8];
    const float* fcw  = (const float*)d_in[9];
    const float* fcb  = (const float*)d_in[10];
    float* out = (float*)d_out;

    const int N = in_sizes[0];
    const int E = in_sizes[1] / 2;
    const int G = out_size;
    const int H = 64;

    const int* src = ei;
    const int* dst = ei + E;

    char* p = (char*)d_ws;
    int*   degi   = (int*)p;   p += WS_ALIGN(sizeof(int) * N);
    int*   cursor = (int*)p;   p += WS_ALIGN(sizeof(int) * N);
    int*   start  = (int*)p;   p += WS_ALIGN(sizeof(int) * (N + 1));
    int*   psum   = (int*)p;   p += WS_ALIGN(sizeof(int) * 1024);
    int*   csr    = (int*)p;   p += WS_ALIGN(sizeof(int) * (size_t)E);
    float* dinv   = (float*)p; p += WS_ALIGN(sizeof(float) * N);
    float* xs     = (float*)p; p += WS_ALIGN(sizeof(float) * N);
    float* s      = (float*)p; p += WS_ALIGN(sizeof(float) * N);
    float* bufA   = (float*)p; p += WS_ALIGN(sizeof(float) * (size_t)N * H);
    float* bufB   = (float*)p; p += WS_ALIGN(sizeof(float) * (size_t)N * H);
    float* dots   = (float*)p; p += WS_ALIGN(sizeof(float) * N);
    float* gsum   = (float*)p; p += WS_ALIGN(sizeof(float) * G);
    float* gcnt   = (float*)p; p += WS_ALIGN(sizeof(float) * G);

    const int B = 256;
    int gridN    = (N + B - 1) / B;
    int gridE    = (E + B - 1) / B;
    int gridNH   = (N * H + B - 1) / B;
    int gridWave = (N + 3) / 4;
    int gridG    = (G + B - 1) / B;
    int gridInit = ((N > G ? N : G) + B - 1) / B;
    int nchunks  = (N + 1023) / 1024;
    int gridS3   = (N + 1 + B - 1) / B;
    int gridPool = (N + 1023) / 1024;

    k_init<<<gridInit, B, 0, stream>>>(N, G, degi, cursor, gsum, gcnt);
    k_deg<<<gridE, B, 0, stream>>>(E, dst, degi);
    k_dinv<<<gridN, B, 0, stream>>>(N, degi, x, dinv, xs);
    k_scan1<<<nchunks, B, 0, stream>>>(N, degi, start, psum);
    k_scan2<<<1, B, 0, stream>>>(nchunks, psum);
    k_scan3<<<gridS3, B, 0, stream>>>(N, E, start, psum);
    k_scatter<<<gridE, B, 0, stream>>>(E, src, dst, start, cursor, csr);
    // layer 1 (rank-1)
    k_gather_s<<<gridWave, B, 0, stream>>>(N, start, csr, xs, dinv, s);
    k_h1<<<gridNH, B, 0, stream>>>(N, s, dinv, w1, b1, bufA);
    // layer 2 fused: gather(hs1) + GEMM(w2) -> hs2
    k_layer<<<gridWave, B, 0, stream>>>(N, start, csr, bufA, dinv, w2, b2, bufB);
    // layer 3 fused: gather(hs2) + GEMM(w3) + relu + fc-dot -> dots
    k_layer_final<<<gridWave, B, 0, stream>>>(N, start, csr, bufB, dinv, w3, b3, fcw, dots);
    // pooling + head
    k_pool<<<gridPool, B, 0, stream>>>(N, dots, batch, gsum, gcnt);
    k_out<<<gridG, B, 0, stream>>>(G, gsum, gcnt, fcb, out);
}